// Round 6
// baseline (451.745 us; speedup 1.0000x reference)
//
#include <hip/hip_runtime.h>
#include <math.h>

#define H 512
#define W 512
#define S (H*W)            // 262144 points per plane
#define BS 16
#define CH 3
#define NP (BS*CH)         // 48 planes
#define WCS ((H-1)*W)      // weights_col per-batch stride (511*512)
#define WRS (H*(W-1))      // weights_row per-batch stride (512*511)
#define WRROW (W-1)        // weights_row row stride (511)
#define STRIP 8            // interior rows per block
#define EXTR (STRIP + 2)   // extended rows for step-1 (halo 1)
#define LROW 520           // LDS row stride (floats); data cols 4..515; 520*4%16==0

// Channel-fused 2-step Chebyshev-node Richardson.
// Block = (batch, 8-row strip) x all 3 channels -> weights loaded once, used
// 3x (x2 steps). Step 1: 2 threads/column march 5 extended rows each with a
// 3-row x-window in registers (7 row loads per 5 rows) -> LDS x1[3 ch].
// Step 2: 8 interior rows from LDS -> global. LDS 62.4 KB -> 2 blocks/CU.
__global__ void __launch_bounds__(256)
cheb2(const float* __restrict__ XS, float* __restrict__ XD,
      const float* __restrict__ Bp, const float* __restrict__ WC,
      const float* __restrict__ WR, float ta, float tb)
{
  __shared__ float x1[CH][EXTR][LROW];   // 62400 B
  const int bb  = blockIdx.y;            // batch 0..15
  const int y0  = blockIdx.x * STRIP;
  const int tid = (int)threadIdx.x;

  const float* wcb = WC + (size_t)bb * WCS;
  const float* wrb = WR + (size_t)bb * WRS;
  const float* xp0 = XS + (size_t)(bb * CH) * S;
  const float* bp0 = Bp + (size_t)(bb * CH) * S;
  float* xd0 = XD + (size_t)(bb * CH) * S;

  const float4 z4 = make_float4(0.f, 0.f, 0.f, 0.f);

  // ---- step 1: vertical march, 5 ext rows per thread, 3 channels ----
  {
    const int c4 = (tid & 127) << 2;     // column 0,4,...,508
    const int h  = tid >> 7;             // 0: ext rows 0..4, 1: ext rows 5..9
    const int ys = y0 - 1 + 5 * h;       // y of first computed ext row

    float4 xm[CH], xc[CH], xp[CH];
#pragma unroll
    for (int c = 0; c < CH; ++c) {
      xm[c] = (ys - 1 >= 0 && ys - 1 < H)
                ? *(const float4*)(xp0 + (size_t)c * S + (ys - 1) * W + c4) : z4;
      xc[c] = (ys >= 0 && ys < H)
                ? *(const float4*)(xp0 + (size_t)c * S + ys * W + c4) : z4;
    }
#pragma unroll
    for (int k = 0; k < 5; ++k) {
      const int y  = ys + k;
      const int rh = 5 * h + k;
#pragma unroll
      for (int c = 0; c < CH; ++c)
        xp[c] = (y + 1 >= 0 && y + 1 < H)
                  ? *(const float4*)(xp0 + (size_t)c * S + (y + 1) * W + c4) : z4;
      float4 o[CH] = {z4, z4, z4};
      if (y >= 0 && y < H) {
        const int t = y * W + c4;
        const float4 wu = (y > 0)     ? *(const float4*)(wcb + t - W) : z4;
        const float4 wd = (y < H - 1) ? *(const float4*)(wcb + t)     : z4;
        const float* wrow = wrb + (size_t)y * WRROW;
        const float wl0 = (c4 > 0) ? wrow[c4 - 1] : 0.f;
        const float w0 = wrow[c4], w1 = wrow[c4 + 1], w2 = wrow[c4 + 2];
        const float w3 = (c4 + 3 < W - 1) ? wrow[c4 + 3] : 0.f;
        const float4 wl = make_float4(wl0, w0, w1, w2);
        const float4 wr = make_float4(w0, w1, w2, w3);
#pragma unroll
        for (int c = 0; c < CH; ++c) {
          const float xlm = (c4 > 0)     ? xp0[(size_t)c * S + t - 1] : 0.f;
          const float xrp = (c4 + 4 < W) ? xp0[(size_t)c * S + t + 4] : 0.f;
          const float4 bv = *(const float4*)(bp0 + (size_t)c * S + t);
          const float4 xl = make_float4(xlm, xc[c].x, xc[c].y, xc[c].z);
          const float4 xr = make_float4(xc[c].y, xc[c].z, xc[c].w, xrp);
#define ELEM(f) {                                                        \
            const float kv = 1.f + wu.f + wd.f + wl.f + wr.f;            \
            const float av = kv * xc[c].f - wu.f * xm[c].f               \
                             - wd.f * xp[c].f - wl.f * xl.f - wr.f * xr.f; \
            o[c].f = xc[c].f + ta * (bv.f - av); }
          ELEM(x) ELEM(y) ELEM(z) ELEM(w)
#undef ELEM
        }
      }
#pragma unroll
      for (int c = 0; c < CH; ++c) {
        *(float4*)&x1[c][rh][4 + c4] = o[c];
        if (c4 == 0)   x1[c][rh][3]   = 0.f;
        if (c4 == 508) x1[c][rh][516] = 0.f;
        xm[c] = xc[c]; xc[c] = xp[c];
      }
    }
  }
  __syncthreads();

  // ---- step 2: 8 interior rows from LDS -> global, 3 channels ----
  for (int it = tid; it < STRIP * 128; it += 256) {
    const int rr = it >> 7;              // 0..7
    const int c4 = (it & 127) << 2;
    const int y  = y0 + rr;
    const int l  = rr + 1;
    const int t  = y * W + c4;

    const float4 wu = (y > 0)     ? *(const float4*)(wcb + t - W) : z4;
    const float4 wd = (y < H - 1) ? *(const float4*)(wcb + t)     : z4;
    const float* wrow = wrb + (size_t)y * WRROW;
    const float wl0 = (c4 > 0) ? wrow[c4 - 1] : 0.f;
    const float w0 = wrow[c4], w1 = wrow[c4 + 1], w2 = wrow[c4 + 2];
    const float w3 = (c4 + 3 < W - 1) ? wrow[c4 + 3] : 0.f;
    const float4 wl = make_float4(wl0, w0, w1, w2);
    const float4 wr = make_float4(w0, w1, w2, w3);

#pragma unroll
    for (int c = 0; c < CH; ++c) {
      const float4 xc = *(const float4*)&x1[c][l][4 + c4];
      const float4 xu = *(const float4*)&x1[c][l - 1][4 + c4];
      const float4 xd = *(const float4*)&x1[c][l + 1][4 + c4];
      const float4 l4 = *(const float4*)&x1[c][l][c4];      // use .w
      const float4 r4 = *(const float4*)&x1[c][l][8 + c4];  // use .x
      const float4 xl = make_float4(l4.w, xc.x, xc.y, xc.z);
      const float4 xr = make_float4(xc.y, xc.z, xc.w, r4.x);
      const float4 bv = *(const float4*)(bp0 + (size_t)c * S + t);
      float4 out;
#define ELEM(f) {                                                        \
        const float kv = 1.f + wu.f + wd.f + wl.f + wr.f;                \
        const float av = kv * xc.f - wu.f * xu.f - wd.f * xd.f           \
                         - wl.f * xl.f - wr.f * xr.f;                    \
        out.f = xc.f + tb * (bv.f - av); }
      ELEM(x) ELEM(y) ELEM(z) ELEM(w)
#undef ELEM
      *(float4*)(xd0 + (size_t)c * S + t) = out;
    }
  }
}

extern "C" void kernel_launch(void* const* d_in, const int* in_sizes, int n_in,
                              void* d_out, int out_size, void* d_ws, size_t ws_size,
                              hipStream_t stream) {
  const float* Bp = (const float*)d_in[0];
  const float* WC = (const float*)d_in[1];
  const float* WR = (const float*)d_in[2];
  float* Xout = (float*)d_out;
  float* bufA = (float*)d_ws;          // 50 MB ping buffer

  // 12 Chebyshev nodes on [1,9]; residual poly max 1/T_12(1.25) ~= 9.8e-4.
  // Conjugate-pair order -> bounded intermediates, fp32-stable.
  const int ord[12] = {1,12, 6,7, 3,10, 4,9, 2,11, 5,8};
  float tau[12];
  for (int i = 0; i < 12; ++i) {
    const double lam = 5.0 + 4.0 * cos(M_PI * (2.0 * ord[i] - 1.0) / 24.0);
    tau[i] = (float)(1.0 / lam);
  }

  dim3 grid(H / STRIP, BS), block(256);
  const float* src = Bp;               // x_0 = B
  for (int i = 0; i < 6; ++i) {
    float* dst = (i & 1) ? Xout : bufA;            // i=5 -> Xout holds x_12
    cheb2<<<grid, block, 0, stream>>>(src, dst, Bp, WC, WR,
                                      tau[2 * i], tau[2 * i + 1]);
    src = dst;
  }
}